// Round 11
// baseline (288.536 us; speedup 1.0000x reference)
//
#include <hip/hip_runtime.h>
#include <hip/hip_bf16.h>

// Problem constants (from reference setup_inputs)
#define BDIM 256     // batch
#define NDIM 1152    // route nodes
#define CIN 8
#define KDIM 10      // num capsule groups
#define COUT 16
#define NTHREADS 512
#define BT 2         // batches per block -> W[k] read once per 2 b's
#define NPT 9        // n values per thread = NDIM / 128

// Block = (k, b-pair). Thread t owns co-quad coq=t&3 at n = (t>>2)+128j.
// R11 structural change: pred NEVER touches LDS. Thread (nb,coq) both wrote
// and read predS[n*4+coq] in R4-R9 -- the 74 KB buffer was only a register
// spill valve costing 27 DS ops/thread and pinning LDS occupancy to
// 2 blocks/CU. Now pred lives in uint4 p[9] (bf16x2-packed, both batches,
// 36 VGPR) with fully-unrolled j-loops (static indices -> registers).
// LDS shrinks to 5 KB (cross-wave reduction buffers only) -> occupancy is
// register-bound: <=85 VGPR gives 3 blocks/CU = 24 waves/CU.
//
// Register discipline (R5-R10 lessons): spills come from load BATCHING.
//  - intra-j sched_barrier(0) fences every 2 W float4 loads (R9: 52 VGPR)
//  - fence at end of each j stops cross-j hoisting
//  - amdgpu_waves_per_eu(6,8): target 6 waves/EU (85 VGPR cap); R10 showed
//    the attribute does steer the allocator ((2,2) -> 88 VGPR).
// W loads: float4, 4 coq-lanes cover each 64B line exactly once.
// No max-subtraction in softmax (|p*vc| << 88). Squash in one division:
// v = s|s|/(1+s^2), s = sp/se  ==  sp*|sp|/(se^2+sp^2)   (se > 0 always).

#if defined(__has_builtin)
#  if __has_builtin(__builtin_amdgcn_exp2f)
#    define EXP2F(x) __builtin_amdgcn_exp2f(x)
#  endif
#  if __has_builtin(__builtin_amdgcn_rcpf)
#    define RCPF(x) __builtin_amdgcn_rcpf(x)
#  endif
#endif
#ifndef EXP2F
#  define EXP2F(x) exp2f(x)
#endif
#ifndef RCPF
#  define RCPF(x) (1.0f / (x))
#endif
#define LOG2E 1.4426950408889634f

__device__ __forceinline__ unsigned pack2(float a, float b) {   // v_cvt_pk_bf16_f32
    union { __hip_bfloat162 h; unsigned u; } cv;
    cv.h = __float22bfloat162_rn(make_float2(a, b));
    return cv.u;
}
__device__ __forceinline__ float bf_lo(unsigned u) { return __uint_as_float(u << 16); }
__device__ __forceinline__ float bf_hi(unsigned u) { return __uint_as_float(u & 0xffff0000u); }

// 8 FMAs: one W float4 (one i) against both batches' x scalar
#define FMA8(i, w4)                                                      \
    a0[0] = fmaf(xs0[i], (w4).x, a0[0]);                                 \
    a0[1] = fmaf(xs0[i], (w4).y, a0[1]);                                 \
    a0[2] = fmaf(xs0[i], (w4).z, a0[2]);                                 \
    a0[3] = fmaf(xs0[i], (w4).w, a0[3]);                                 \
    a1[0] = fmaf(xs1[i], (w4).x, a1[0]);                                 \
    a1[1] = fmaf(xs1[i], (w4).y, a1[1]);                                 \
    a1[2] = fmaf(xs1[i], (w4).z, a1[2]);                                 \
    a1[3] = fmaf(xs1[i], (w4).w, a1[3]);

__global__ __attribute__((amdgpu_flat_work_group_size(NTHREADS, NTHREADS),
                          amdgpu_waves_per_eu(6, 8)))
void capsule_routing_kernel(const float* __restrict__ x,      // [B, N, CIN]
                            const float* __restrict__ w,      // [K, N, CIN, COUT]
                            const int*   __restrict__ niter_p,
                            float*       __restrict__ out)    // [K, B, COUT]
{
    __shared__ float4 redP[8][4][2];       // [wv][coq][bb] psum, 1 KB
    __shared__ float4 redI[2][8][4][4];    // [buf][wv][coq][{se0,sp0,se1,sp1}], 4 KB

    const int blk = blockIdx.x;
    const int k   = blk >> 7;              // / (BDIM/BT) == 128
    const int b0  = (blk & 127) * BT;
    const int t   = threadIdx.x;
    const int wv  = t >> 6;
    const int l   = t & 63;
    const int coq = t & 3;                 // co = coq*4 .. coq*4+3
    const int nb  = t >> 2;                // base n (0..127)

    const float* __restrict__ xb0 = x + (size_t)b0 * NDIM * CIN;
    const float* __restrict__ xb1 = xb0 + NDIM * CIN;
    const float* __restrict__ wk  = w + (size_t)k * NDIM * CIN * COUT + coq * 4;

    uint4 p[NPT];                          // bf16x2 pred: {b0c01,b0c23,b1c01,b1c23}
    float ps0[4] = {0.f,0.f,0.f,0.f}, ps1[4] = {0.f,0.f,0.f,0.f};

    // -------- Phase 1: pred (registers!) + fused per-thread sum --------
#pragma unroll
    for (int j = 0; j < NPT; ++j) {
        const int n = nb + 128 * j;
        const float4 xa0 = *reinterpret_cast<const float4*>(xb0 + n * CIN);
        const float4 xc0 = *reinterpret_cast<const float4*>(xb0 + n * CIN + 4);
        const float4 xa1 = *reinterpret_cast<const float4*>(xb1 + n * CIN);
        const float4 xc1 = *reinterpret_cast<const float4*>(xb1 + n * CIN + 4);
        const float xs0[8] = {xa0.x,xa0.y,xa0.z,xa0.w,xc0.x,xc0.y,xc0.z,xc0.w};
        const float xs1[8] = {xa1.x,xa1.y,xa1.z,xa1.w,xc1.x,xc1.y,xc1.z,xc1.w};
        const float* wr = wk + (size_t)n * (CIN * COUT);
        float a0[4] = {0.f,0.f,0.f,0.f}, a1[4] = {0.f,0.f,0.f,0.f};
        {   // i = 0,1
            const float4 wA = *reinterpret_cast<const float4*>(wr);
            const float4 wB = *reinterpret_cast<const float4*>(wr + COUT);
            FMA8(0, wA); FMA8(1, wB);
        }
        __builtin_amdgcn_sched_barrier(0);  // bound W loads in flight to 2
        {   // i = 2,3
            const float4 wA = *reinterpret_cast<const float4*>(wr + 2 * COUT);
            const float4 wB = *reinterpret_cast<const float4*>(wr + 3 * COUT);
            FMA8(2, wA); FMA8(3, wB);
        }
        __builtin_amdgcn_sched_barrier(0);
        {   // i = 4,5
            const float4 wA = *reinterpret_cast<const float4*>(wr + 4 * COUT);
            const float4 wB = *reinterpret_cast<const float4*>(wr + 5 * COUT);
            FMA8(4, wA); FMA8(5, wB);
        }
        __builtin_amdgcn_sched_barrier(0);
        {   // i = 6,7
            const float4 wA = *reinterpret_cast<const float4*>(wr + 6 * COUT);
            const float4 wB = *reinterpret_cast<const float4*>(wr + 7 * COUT);
            FMA8(6, wA); FMA8(7, wB);
        }
        p[j].x = pack2(a0[0], a0[1]);
        p[j].y = pack2(a0[2], a0[3]);
        p[j].z = pack2(a1[0], a1[1]);
        p[j].w = pack2(a1[2], a1[3]);
#pragma unroll
        for (int c = 0; c < 4; ++c) { ps0[c] += a0[c]; ps1[c] += a1[c]; }
        __builtin_amdgcn_sched_barrier(0);  // stop cross-j load hoisting
    }

    // intra-wave reduce over the 16 lanes sharing coq
#pragma unroll
    for (int m = 4; m < 64; m <<= 1) {
#pragma unroll
        for (int c = 0; c < 4; ++c) {
            ps0[c] += __shfl_xor(ps0[c], m, 64);
            ps1[c] += __shfl_xor(ps1[c], m, 64);
        }
    }
    if (l < 4) {                            // lane l holds coq == l
        redP[wv][l][0] = make_float4(ps0[0], ps0[1], ps0[2], ps0[3]);
        redP[wv][l][1] = make_float4(ps1[0], ps1[1], ps1[2], ps1[3]);
    }
    __syncthreads();
    float sT0[4] = {0.f,0.f,0.f,0.f}, sT1[4] = {0.f,0.f,0.f,0.f};
#pragma unroll 1
    for (int wvi = 0; wvi < 8; ++wvi) {    // unroll 1: bound LDS-read batching
        const float4 r0 = redP[wvi][coq][0];
        const float4 r1 = redP[wvi][coq][1];
        sT0[0] += r0.x; sT0[1] += r0.y; sT0[2] += r0.z; sT0[3] += r0.w;
        sT1[0] += r1.x; sT1[1] += r1.y; sT1[2] += r1.z; sT1[3] += r1.w;
    }

    const int niter = *niter_p;

    // Iteration 1: logits == 0 -> uniform softmax -> s = mean_n(pred)
    // v = s|s|/(1+s^2), s = sT/N  ==  sT*|sT| / (N^2 + sT^2)
    float v0[4], v1[4], vc0[4], vc1[4];
    {
        const float N2 = (float)NDIM * (float)NDIM;
#pragma unroll
        for (int c = 0; c < 4; ++c) {
            v0[c] = sT0[c] * fabsf(sT0[c]) * RCPF(fmaf(sT0[c], sT0[c], N2));
            v1[c] = sT1[c] * fabsf(sT1[c]) * RCPF(fmaf(sT1[c], sT1[c], N2));
            vc0[c] = v0[c];
            vc1[c] = v1[c];
        }
    }

    for (int it = 1; it < niter; ++it) {
        const int itb = it & 1;
        // fold log2(e) into vc once: exp(p*vc) == exp2(p * (vc*log2e))
        float vl0[4], vl1[4];
#pragma unroll
        for (int c = 0; c < 4; ++c) { vl0[c] = vc0[c] * LOG2E; vl1[c] = vc1[c] * LOG2E; }

        float se0[4]={0.f,0.f,0.f,0.f}, sp0[4]={0.f,0.f,0.f,0.f};
        float se1[4]={0.f,0.f,0.f,0.f}, sp1[4]={0.f,0.f,0.f,0.f};
#pragma unroll
        for (int j = 0; j < NPT; ++j) {    // pred from REGISTERS, no LDS
            const uint4 q = p[j];
            const float p0[4] = {bf_lo(q.x), bf_hi(q.x), bf_lo(q.y), bf_hi(q.y)};
            const float p1[4] = {bf_lo(q.z), bf_hi(q.z), bf_lo(q.w), bf_hi(q.w)};
#pragma unroll
            for (int c = 0; c < 4; ++c) {
                const float e0 = EXP2F(p0[c] * vl0[c]);   // bare v_exp_f32
                se0[c] += e0;
                sp0[c] = fmaf(e0, p0[c], sp0[c]);
                const float e1 = EXP2F(p1[c] * vl1[c]);
                se1[c] += e1;
                sp1[c] = fmaf(e1, p1[c], sp1[c]);
            }
        }
#pragma unroll
        for (int m = 4; m < 64; m <<= 1) {
#pragma unroll
            for (int c = 0; c < 4; ++c) {
                se0[c] += __shfl_xor(se0[c], m, 64);
                sp0[c] += __shfl_xor(sp0[c], m, 64);
                se1[c] += __shfl_xor(se1[c], m, 64);
                sp1[c] += __shfl_xor(sp1[c], m, 64);
            }
        }
        if (l < 4) {
            redI[itb][wv][l][0] = make_float4(se0[0], se0[1], se0[2], se0[3]);
            redI[itb][wv][l][1] = make_float4(sp0[0], sp0[1], sp0[2], sp0[3]);
            redI[itb][wv][l][2] = make_float4(se1[0], se1[1], se1[2], se1[3]);
            redI[itb][wv][l][3] = make_float4(sp1[0], sp1[1], sp1[2], sp1[3]);
        }
        __syncthreads();   // double-buffered redI: one barrier per iteration
        float seT0[4]={0.f,0.f,0.f,0.f}, spT0[4]={0.f,0.f,0.f,0.f};
        float seT1[4]={0.f,0.f,0.f,0.f}, spT1[4]={0.f,0.f,0.f,0.f};
#pragma unroll 1
        for (int wvi = 0; wvi < 8; ++wvi) {   // unroll 1: <=4 float4 live
            const float4 a = redI[itb][wvi][coq][0];
            const float4 b = redI[itb][wvi][coq][1];
            const float4 c4 = redI[itb][wvi][coq][2];
            const float4 d = redI[itb][wvi][coq][3];
            seT0[0]+=a.x; seT0[1]+=a.y; seT0[2]+=a.z; seT0[3]+=a.w;
            spT0[0]+=b.x; spT0[1]+=b.y; spT0[2]+=b.z; spT0[3]+=b.w;
            seT1[0]+=c4.x; seT1[1]+=c4.y; seT1[2]+=c4.z; seT1[3]+=c4.w;
            spT1[0]+=d.x; spT1[1]+=d.y; spT1[2]+=d.z; spT1[3]+=d.w;
        }
        // v = sp*|sp| / (se^2 + sp^2); vc += v   (se > 0 always)
#pragma unroll
        for (int c = 0; c < 4; ++c) {
            v0[c] = spT0[c] * fabsf(spT0[c]) *
                    RCPF(fmaf(seT0[c], seT0[c], spT0[c] * spT0[c]));
            v1[c] = spT1[c] * fabsf(spT1[c]) *
                    RCPF(fmaf(seT1[c], seT1[c], spT1[c] * spT1[c]));
            vc0[c] += v0[c];
            vc1[c] += v1[c];
        }
    }

    if (t < 4) {   // coq == t
        float4 o0, o1;
        o0.x = v0[0]; o0.y = v0[1]; o0.z = v0[2]; o0.w = v0[3];
        o1.x = v1[0]; o1.y = v1[1]; o1.z = v1[2]; o1.w = v1[3];
        *reinterpret_cast<float4*>(out + ((size_t)k * BDIM + b0)     * COUT + t * 4) = o0;
        *reinterpret_cast<float4*>(out + ((size_t)k * BDIM + b0 + 1) * COUT + t * 4) = o1;
    }
}

extern "C" void kernel_launch(void* const* d_in, const int* in_sizes, int n_in,
                              void* d_out, int out_size, void* d_ws, size_t ws_size,
                              hipStream_t stream) {
    const float* x = (const float*)d_in[0];
    const float* w = (const float*)d_in[1];
    const int* niter = (const int*)d_in[2];
    float* out = (float*)d_out;

    const int grid = KDIM * (BDIM / BT);   // 1280 blocks, k outer
    capsule_routing_kernel<<<grid, NTHREADS, 0, stream>>>(x, w, niter, out);
}

// Round 12
// 71.860 us; speedup vs baseline: 4.0152x; 4.0152x over previous
//
#include <hip/hip_runtime.h>
#include <hip/hip_bf16.h>

// Problem constants (from reference setup_inputs)
#define BDIM 256     // batch
#define NDIM 1152    // route nodes
#define CIN 8
#define KDIM 10      // num capsule groups
#define COUT 16
#define NTHREADS 512
#define BT 2         // batches per block -> W[k] read once per 2 b's
#define NPT 9        // n values per thread = NDIM / 128

// Block = (k, b-pair). Thread t owns co-quad coq=t&3 at n = (t>>2)+128j.
// pred: bf16x2 in LDS, uint4 per (n,coq) -> ds_read/write_b128 at 16*lane
// (conflict-free). W loads: float4, 4 coq-lanes cover each 64B line once.
// No max-subtraction (|p*vc| << 88). Single-division squash:
// v = s|s|/(1+s^2), s = sp/se == sp*|sp|/(se^2+sp^2)  (se > 0).
//
// R12: packed f32 math. CDNA4 has v_pk_fma_f32 / v_pk_add_f32 / v_pk_mul_f32
// (2 f32 ops per instruction). Reached from HIP via ext_vector_type(2) +
// __builtin_elementwise_fma / vector +,* (clang lowers v2f32 fma/fadd/fmul
// to pk ops on gfx90a+). Halves phase-1 FMA instr count and the iteration
// mul/add/fma count.
//
// Spill discipline (R5-R11): spills come from load BATCHING; waves_per_eu
// must pin a SINGLE target (range lets the allocator pick the high end ->
// R11's 40-VGPR disaster). (4,4) + intra-j sched_barrier(0) fences = R9's
// proven 52-VGPR no-spill config.

#if defined(__has_builtin)
#  if __has_builtin(__builtin_amdgcn_exp2f)
#    define EXP2F(x) __builtin_amdgcn_exp2f(x)
#  endif
#  if __has_builtin(__builtin_amdgcn_rcpf)
#    define RCPF(x) __builtin_amdgcn_rcpf(x)
#  endif
#endif
#ifndef EXP2F
#  define EXP2F(x) exp2f(x)
#endif
#ifndef RCPF
#  define RCPF(x) (1.0f / (x))
#endif
#define LOG2E 1.4426950408889634f

typedef float f32x2 __attribute__((ext_vector_type(2)));

__device__ __forceinline__ f32x2 pkfma(f32x2 a, f32x2 b, f32x2 c) {
#if defined(__has_builtin) && __has_builtin(__builtin_elementwise_fma)
    return __builtin_elementwise_fma(a, b, c);
#else
    f32x2 r; r.x = fmaf(a.x, b.x, c.x); r.y = fmaf(a.y, b.y, c.y); return r;
#endif
}

__device__ __forceinline__ unsigned pack2(float a, float b) {   // v_cvt_pk_bf16_f32
    union { __hip_bfloat162 h; unsigned u; } cv;
    cv.h = __float22bfloat162_rn(make_float2(a, b));
    return cv.u;
}
__device__ __forceinline__ float bf_lo(unsigned u) { return __uint_as_float(u << 16); }
__device__ __forceinline__ float bf_hi(unsigned u) { return __uint_as_float(u & 0xffff0000u); }

// 8 FMAs as 4 v_pk_fma_f32: one W float4 (one i) against both batches
#define PKFMA8(i, w4)                                                    \
    {                                                                    \
        const f32x2 wlo = {(w4).x, (w4).y};                              \
        const f32x2 whi = {(w4).z, (w4).w};                              \
        const f32x2 x0v = {xs0[i], xs0[i]};                              \
        const f32x2 x1v = {xs1[i], xs1[i]};                              \
        A0lo = pkfma(x0v, wlo, A0lo);                                    \
        A0hi = pkfma(x0v, whi, A0hi);                                    \
        A1lo = pkfma(x1v, wlo, A1lo);                                    \
        A1hi = pkfma(x1v, whi, A1hi);                                    \
    }

__global__ __attribute__((amdgpu_flat_work_group_size(NTHREADS, NTHREADS),
                          amdgpu_waves_per_eu(4, 4)))
void capsule_routing_kernel(const float* __restrict__ x,      // [B, N, CIN]
                            const float* __restrict__ w,      // [K, N, CIN, COUT]
                            const int*   __restrict__ niter_p,
                            float*       __restrict__ out)    // [K, B, COUT]
{
    __shared__ uint4  predS[NDIM * 4];     // [n][coq] = {b0c01,b0c23,b1c01,b1c23}, 73728 B
    __shared__ float4 redP[8][4][2];       // [wv][coq][bb] psum, 1 KB
    __shared__ float4 redI[2][8][4][4];    // [buf][wv][coq][{se0,sp0,se1,sp1}], 4 KB

    const int blk = blockIdx.x;
    const int k   = blk >> 7;              // / (BDIM/BT) == 128
    const int b0  = (blk & 127) * BT;
    const int t   = threadIdx.x;
    const int wv  = t >> 6;
    const int l   = t & 63;
    const int coq = t & 3;                 // co = coq*4 .. coq*4+3
    const int nb  = t >> 2;                // base n (0..127)

    const float* __restrict__ xb0 = x + (size_t)b0 * NDIM * CIN;
    const float* __restrict__ xb1 = xb0 + NDIM * CIN;
    const float* __restrict__ wk  = w + (size_t)k * NDIM * CIN * COUT + coq * 4;

    f32x2 PS0lo = {0.f,0.f}, PS0hi = {0.f,0.f};
    f32x2 PS1lo = {0.f,0.f}, PS1hi = {0.f,0.f};

    // -------- Phase 1: pred for both batches + fused per-thread sum --------
#pragma unroll 1
    for (int j = 0; j < NPT; ++j) {
        const int n = nb + 128 * j;
        const float4 xa0 = *reinterpret_cast<const float4*>(xb0 + n * CIN);
        const float4 xc0 = *reinterpret_cast<const float4*>(xb0 + n * CIN + 4);
        const float4 xa1 = *reinterpret_cast<const float4*>(xb1 + n * CIN);
        const float4 xc1 = *reinterpret_cast<const float4*>(xb1 + n * CIN + 4);
        const float xs0[8] = {xa0.x,xa0.y,xa0.z,xa0.w,xc0.x,xc0.y,xc0.z,xc0.w};
        const float xs1[8] = {xa1.x,xa1.y,xa1.z,xa1.w,xc1.x,xc1.y,xc1.z,xc1.w};
        const float* wr = wk + (size_t)n * (CIN * COUT);
        f32x2 A0lo = {0.f,0.f}, A0hi = {0.f,0.f};
        f32x2 A1lo = {0.f,0.f}, A1hi = {0.f,0.f};
        {   // i = 0,1
            const float4 wA = *reinterpret_cast<const float4*>(wr);
            const float4 wB = *reinterpret_cast<const float4*>(wr + COUT);
            PKFMA8(0, wA); PKFMA8(1, wB);
        }
        __builtin_amdgcn_sched_barrier(0);  // bound W loads in flight to 2
        {   // i = 2,3
            const float4 wA = *reinterpret_cast<const float4*>(wr + 2 * COUT);
            const float4 wB = *reinterpret_cast<const float4*>(wr + 3 * COUT);
            PKFMA8(2, wA); PKFMA8(3, wB);
        }
        __builtin_amdgcn_sched_barrier(0);
        {   // i = 4,5
            const float4 wA = *reinterpret_cast<const float4*>(wr + 4 * COUT);
            const float4 wB = *reinterpret_cast<const float4*>(wr + 5 * COUT);
            PKFMA8(4, wA); PKFMA8(5, wB);
        }
        __builtin_amdgcn_sched_barrier(0);
        {   // i = 6,7
            const float4 wA = *reinterpret_cast<const float4*>(wr + 6 * COUT);
            const float4 wB = *reinterpret_cast<const float4*>(wr + 7 * COUT);
            PKFMA8(6, wA); PKFMA8(7, wB);
        }
        uint4 qq;
        qq.x = pack2(A0lo.x, A0lo.y);
        qq.y = pack2(A0hi.x, A0hi.y);
        qq.z = pack2(A1lo.x, A1lo.y);
        qq.w = pack2(A1hi.x, A1hi.y);
        predS[n * 4 + coq] = qq;           // ds_write_b128, addr = 16*lane
        PS0lo += A0lo; PS0hi += A0hi;      // v_pk_add_f32
        PS1lo += A1lo; PS1hi += A1hi;
        __builtin_amdgcn_sched_barrier(0);  // stop cross-j load hoisting
    }

    // intra-wave reduce over the 16 lanes sharing coq (pk adds)
#pragma unroll
    for (int m = 4; m < 64; m <<= 1) {
        f32x2 u;
        u.x = __shfl_xor(PS0lo.x, m, 64); u.y = __shfl_xor(PS0lo.y, m, 64);
        PS0lo += u;
        u.x = __shfl_xor(PS0hi.x, m, 64); u.y = __shfl_xor(PS0hi.y, m, 64);
        PS0hi += u;
        u.x = __shfl_xor(PS1lo.x, m, 64); u.y = __shfl_xor(PS1lo.y, m, 64);
        PS1lo += u;
        u.x = __shfl_xor(PS1hi.x, m, 64); u.y = __shfl_xor(PS1hi.y, m, 64);
        PS1hi += u;
    }
    if (l < 4) {                            // lane l holds coq == l
        redP[wv][l][0] = make_float4(PS0lo.x, PS0lo.y, PS0hi.x, PS0hi.y);
        redP[wv][l][1] = make_float4(PS1lo.x, PS1lo.y, PS1hi.x, PS1hi.y);
    }
    __syncthreads();
    float sT0[4] = {0.f,0.f,0.f,0.f}, sT1[4] = {0.f,0.f,0.f,0.f};
#pragma unroll 1
    for (int wvi = 0; wvi < 8; ++wvi) {    // unroll 1: bound LDS-read batching
        const float4 r0 = redP[wvi][coq][0];
        const float4 r1 = redP[wvi][coq][1];
        sT0[0] += r0.x; sT0[1] += r0.y; sT0[2] += r0.z; sT0[3] += r0.w;
        sT1[0] += r1.x; sT1[1] += r1.y; sT1[2] += r1.z; sT1[3] += r1.w;
    }

    const int niter = *niter_p;

    // Iteration 1: logits == 0 -> uniform softmax -> s = mean_n(pred)
    // v = s|s|/(1+s^2), s = sT/N == sT*|sT| / (N^2 + sT^2)
    float v0[4], v1[4], vc0[4], vc1[4];
    {
        const float N2 = (float)NDIM * (float)NDIM;
#pragma unroll
        for (int c = 0; c < 4; ++c) {
            v0[c] = sT0[c] * fabsf(sT0[c]) * RCPF(fmaf(sT0[c], sT0[c], N2));
            v1[c] = sT1[c] * fabsf(sT1[c]) * RCPF(fmaf(sT1[c], sT1[c], N2));
            vc0[c] = v0[c];
            vc1[c] = v1[c];
        }
    }

    for (int it = 1; it < niter; ++it) {
        const int itb = it & 1;
        // fold log2(e) into vc: exp(p*vc) == exp2(p * (vc*log2e))
        f32x2 VL0lo = {vc0[0] * LOG2E, vc0[1] * LOG2E};
        f32x2 VL0hi = {vc0[2] * LOG2E, vc0[3] * LOG2E};
        f32x2 VL1lo = {vc1[0] * LOG2E, vc1[1] * LOG2E};
        f32x2 VL1hi = {vc1[2] * LOG2E, vc1[3] * LOG2E};

        f32x2 SE0lo = {0.f,0.f}, SE0hi = {0.f,0.f};
        f32x2 SE1lo = {0.f,0.f}, SE1hi = {0.f,0.f};
        f32x2 SP0lo = {0.f,0.f}, SP0hi = {0.f,0.f};
        f32x2 SP1lo = {0.f,0.f}, SP1hi = {0.f,0.f};
#pragma unroll 3
        for (int j = 0; j < NPT; ++j) {
            const int n = nb + 128 * j;
            const uint4 q = predS[n * 4 + coq];   // ds_read_b128, conflict-free
            const f32x2 P0lo = {bf_lo(q.x), bf_hi(q.x)};
            const f32x2 P0hi = {bf_lo(q.y), bf_hi(q.y)};
            const f32x2 P1lo = {bf_lo(q.z), bf_hi(q.z)};
            const f32x2 P1hi = {bf_lo(q.w), bf_hi(q.w)};
            const f32x2 T0lo = P0lo * VL0lo;      // v_pk_mul_f32
            const f32x2 T0hi = P0hi * VL0hi;
            const f32x2 T1lo = P1lo * VL1lo;
            const f32x2 T1hi = P1hi * VL1hi;
            const f32x2 E0lo = {EXP2F(T0lo.x), EXP2F(T0lo.y)};
            const f32x2 E0hi = {EXP2F(T0hi.x), EXP2F(T0hi.y)};
            const f32x2 E1lo = {EXP2F(T1lo.x), EXP2F(T1lo.y)};
            const f32x2 E1hi = {EXP2F(T1hi.x), EXP2F(T1hi.y)};
            SE0lo += E0lo; SE0hi += E0hi;         // v_pk_add_f32
            SE1lo += E1lo; SE1hi += E1hi;
            SP0lo = pkfma(E0lo, P0lo, SP0lo);     // v_pk_fma_f32
            SP0hi = pkfma(E0hi, P0hi, SP0hi);
            SP1lo = pkfma(E1lo, P1lo, SP1lo);
            SP1hi = pkfma(E1hi, P1hi, SP1hi);
        }
#pragma unroll
        for (int m = 4; m < 64; m <<= 1) {
            f32x2 u;
            u.x = __shfl_xor(SE0lo.x, m, 64); u.y = __shfl_xor(SE0lo.y, m, 64); SE0lo += u;
            u.x = __shfl_xor(SE0hi.x, m, 64); u.y = __shfl_xor(SE0hi.y, m, 64); SE0hi += u;
            u.x = __shfl_xor(SE1lo.x, m, 64); u.y = __shfl_xor(SE1lo.y, m, 64); SE1lo += u;
            u.x = __shfl_xor(SE1hi.x, m, 64); u.y = __shfl_xor(SE1hi.y, m, 64); SE1hi += u;
            u.x = __shfl_xor(SP0lo.x, m, 64); u.y = __shfl_xor(SP0lo.y, m, 64); SP0lo += u;
            u.x = __shfl_xor(SP0hi.x, m, 64); u.y = __shfl_xor(SP0hi.y, m, 64); SP0hi += u;
            u.x = __shfl_xor(SP1lo.x, m, 64); u.y = __shfl_xor(SP1lo.y, m, 64); SP1lo += u;
            u.x = __shfl_xor(SP1hi.x, m, 64); u.y = __shfl_xor(SP1hi.y, m, 64); SP1hi += u;
        }
        if (l < 4) {
            redI[itb][wv][l][0] = make_float4(SE0lo.x, SE0lo.y, SE0hi.x, SE0hi.y);
            redI[itb][wv][l][1] = make_float4(SP0lo.x, SP0lo.y, SP0hi.x, SP0hi.y);
            redI[itb][wv][l][2] = make_float4(SE1lo.x, SE1lo.y, SE1hi.x, SE1hi.y);
            redI[itb][wv][l][3] = make_float4(SP1lo.x, SP1lo.y, SP1hi.x, SP1hi.y);
        }
        __syncthreads();   // double-buffered redI: one barrier per iteration
        float seT0[4]={0.f,0.f,0.f,0.f}, spT0[4]={0.f,0.f,0.f,0.f};
        float seT1[4]={0.f,0.f,0.f,0.f}, spT1[4]={0.f,0.f,0.f,0.f};
#pragma unroll 1
        for (int wvi = 0; wvi < 8; ++wvi) {   // unroll 1: <=4 float4 live
            const float4 a = redI[itb][wvi][coq][0];
            const float4 b = redI[itb][wvi][coq][1];
            const float4 c4 = redI[itb][wvi][coq][2];
            const float4 d = redI[itb][wvi][coq][3];
            seT0[0]+=a.x; seT0[1]+=a.y; seT0[2]+=a.z; seT0[3]+=a.w;
            spT0[0]+=b.x; spT0[1]+=b.y; spT0[2]+=b.z; spT0[3]+=b.w;
            seT1[0]+=c4.x; seT1[1]+=c4.y; seT1[2]+=c4.z; seT1[3]+=c4.w;
            spT1[0]+=d.x; spT1[1]+=d.y; spT1[2]+=d.z; spT1[3]+=d.w;
        }
        // v = sp*|sp| / (se^2 + sp^2); vc += v   (se > 0 always)
#pragma unroll
        for (int c = 0; c < 4; ++c) {
            v0[c] = spT0[c] * fabsf(spT0[c]) *
                    RCPF(fmaf(seT0[c], seT0[c], spT0[c] * spT0[c]));
            v1[c] = spT1[c] * fabsf(spT1[c]) *
                    RCPF(fmaf(seT1[c], seT1[c], spT1[c] * spT1[c]));
            vc0[c] += v0[c];
            vc1[c] += v1[c];
        }
    }

    if (t < 4) {   // coq == t
        float4 o0, o1;
        o0.x = v0[0]; o0.y = v0[1]; o0.z = v0[2]; o0.w = v0[3];
        o1.x = v1[0]; o1.y = v1[1]; o1.z = v1[2]; o1.w = v1[3];
        *reinterpret_cast<float4*>(out + ((size_t)k * BDIM + b0)     * COUT + t * 4) = o0;
        *reinterpret_cast<float4*>(out + ((size_t)k * BDIM + b0 + 1) * COUT + t * 4) = o1;
    }
}

extern "C" void kernel_launch(void* const* d_in, const int* in_sizes, int n_in,
                              void* d_out, int out_size, void* d_ws, size_t ws_size,
                              hipStream_t stream) {
    const float* x = (const float*)d_in[0];
    const float* w = (const float*)d_in[1];
    const int* niter = (const int*)d_in[2];
    float* out = (float*)d_out;

    const int grid = KDIM * (BDIM / BT);   // 1280 blocks, k outer
    capsule_routing_kernel<<<grid, NTHREADS, 0, stream>>>(x, w, niter, out);
}